// Round 18
// baseline (1489.246 us; speedup 1.0000x reference)
//
#include <hip/hip_runtime.h>

#define LL 65536      // H*W
#define KSEL 655      // top-k count
#define EQCAP 8192

typedef unsigned short u16;
typedef __attribute__((ext_vector_type(8))) short s16x8;
typedef __attribute__((ext_vector_type(4))) float f32x4;

#define MFMA16(a,b,c) __builtin_amdgcn_mfma_f32_16x16x32_bf16(a,b,c,0,0,0)

__device__ __forceinline__ u16 f2bf(float v) {
  unsigned u = __float_as_uint(v);
  u += 0x7FFFu + ((u >> 16) & 1u);
  return (u16)(u >> 16);
}
__device__ __forceinline__ float bf2f(u16 h) {
  return __uint_as_float(((unsigned)h) << 16);
}

// ---------------------------------------------------------------------------
// Weight prep bodies (Round-6 verified layouts).
// ---------------------------------------------------------------------------
__device__ void prep_w3_body(int b, const float* __restrict__ up_w,
                             u16* __restrict__ W3, float* lds)
{
  const int cob = b & 3, ciq = (b >> 2) & 15, s = b >> 6;
  const int ci0 = ciq*16, ch = ciq >> 1, k0 = (ciq & 1)*2;
  const int tid = threadIdx.x;
  for (int t = tid; t < 64*144; t += 256) {
    const int co_l = t / 144, r = t - co_l*144;
    lds[co_l*145 + r] = up_w[((size_t)((s*256 + cob*64 + co_l)*256 + ci0))*9 + r];
  }
  __syncthreads();
  for (int u = tid; u < 18432; u += 256) {
    const int within = u & 255, combo = u >> 8;
    const int n = combo & 3, c2 = combo >> 2;
    const int tap = c2 % 9, hl = c2 / 9;
    const int lane_loc = within >> 3, e = within & 7;
    const int lx = lane_loc & 15, kgl = lane_loc >> 4;
    const int co_l = n*16 + lx, ci_l = kgl*8 + e;
    const float v = lds[co_l*145 + ci_l*9 + tap];
    const u16 h = f2bf(v);
    const u16 val = hl ? f2bf(v - bf2f(h)) : h;
    const size_t addr = ((size_t)(((((s*2 + hl)*9 + tap)*4 + cob)*4 + n)*8 + ch))*512
                      + k0*128 + within;
    W3[addr] = val;
  }
}

__device__ void prep_wt_body(int b, const float* __restrict__ ct_w,
                             u16* __restrict__ W4, float* lds)
{
  const int cob = b & 3, ciq = (b >> 2) & 31, s = b >> 7;
  const int ci0 = ciq*8, ch = ciq >> 2, kg = ciq & 3;
  const int tid = threadIdx.x;
  for (int t = tid; t < 8192; t += 256) {
    const int ci_l = t >> 10, r = t & 1023;
    lds[ci_l*1089 + (r >> 4)*17 + (r & 15)] =
        ct_w[((size_t)((s*256 + ci0 + ci_l)*256 + cob*64))*16 + r];
  }
  __syncthreads();
  for (int u = tid; u < 16384; u += 256) {
    const int within = u & 127, combo = u >> 7;
    const int n = combo & 3, pdt = (combo >> 2) & 15, hl = combo >> 6;
    const int lx = within >> 3, e = within & 7;
    const int p = pdt >> 2, dt = pdt & 3;
    const int py = p >> 1, px = p & 1, dy = dt >> 1, dx = dt & 1;
    const int ky = 3 - py - 2*dy, kx = 3 - px - 2*dx;
    const float v = lds[e*1089 + (n*16 + lx)*17 + ky*4 + kx];
    const u16 h = f2bf(v);
    const u16 val = hl ? f2bf(v - bf2f(h)) : h;
    const size_t addr = ((size_t)(((((s*2 + hl)*16 + pdt)*4 + cob)*4 + n)*8 + ch))*512
                      + kg*128 + within;
    W4[addr] = val;
  }
}

__device__ void transpose_body(const float* __restrict__ in, float* __restrict__ out,
                               int R, int Ck, int bx0, int by0, float* lds)
{
  float (*t)[33] = (float(*)[33])lds;
  const int bx = bx0*32, by = by0*32;
  const int x = threadIdx.x & 31, y4 = threadIdx.x >> 5;
  #pragma unroll
  for (int i = 0; i < 4; ++i) {
    int r = by + y4 + i*8, c = bx + x;
    t[y4 + i*8][x] = (r < R && c < Ck) ? in[r*Ck + c] : 0.f;
  }
  __syncthreads();
  #pragma unroll
  for (int i = 0; i < 4; ++i) {
    int c = bx + y4 + i*8, r = by + x;
    if (c < Ck && r < R) out[c*R + r] = t[x][y4 + i*8];
  }
}

// ---------------------------------------------------------------------------
// prep_all: weights + transposes + hist zero + conv1x1 (independent work).
// grid 1281.
// ---------------------------------------------------------------------------
__global__ void __launch_bounds__(256) prep_all(
    const float* __restrict__ up_w, const float* __restrict__ ct_w,
    const float* __restrict__ ipw, const float* __restrict__ ow,
    const float* __restrict__ swinT, const float* __restrict__ wt_w,
    const float* __restrict__ wt_b,
    u16* __restrict__ W3, u16* __restrict__ W4,
    float* __restrict__ WT, float* __restrict__ OWT,
    unsigned* __restrict__ hist, u16* __restrict__ in8)
{
  __shared__ float lds[9280];
  const int b = blockIdx.x;
  if (b < 320)       prep_w3_body(b, up_w, W3, lds);
  else if (b < 960)  prep_wt_body(b - 320, ct_w, W4, lds);
  else if (b < 1152) transpose_body(ipw, WT, 768, 256, (b-960) % 8, (b-960) / 8, lds);
  else if (b < 1216) transpose_body(ow, OWT, 256, 256, (b-1152) % 8, (b-1152) / 8, lds);
  else if (b == 1216) hist[threadIdx.x] = 0;
  else {
    // conv1x1: 4 co per block, 64 pixel threads per co.
    const int co = (b - 1217)*4 + (threadIdx.x >> 6);
    const int pp = threadIdx.x & 63;
    float acc = wt_b[co];
    for (int ci = 0; ci < 768; ++ci)
      acc += swinT[ci*64 + pp] * wt_w[co*768 + ci];
    const int py = pp >> 3, px = pp & 7;
    const int g = co >> 5, cw = co & 31;
    const size_t o = (size_t)g*3200 + ((size_t)((py+1)*10 + px+1))*32 + cw;
    const u16 h = f2bf(acc);
    in8[o] = h;
    in8[o + (size_t)8*3200] = f2bf(acc - bf2f(h));
  }
}

// ---------------------------------------------------------------------------
// zb_copy_gate: zero borders of all padded buffers + copy down -> out
// (blocks 0..4095) + gate+pass0 histogram (blocks 4096..4351).
// ---------------------------------------------------------------------------
__device__ __forceinline__ void zb_dev(u16* __restrict__ buf, int H2, int e)
{
  const int per = (4*H2 - 4)*32;
  const int pl = e / per, r = e - pl*per;
  const int pix = r >> 5, cw = r & 31;
  int y, x;
  if (pix < H2)        { y = 0;      x = pix; }
  else if (pix < 2*H2) { y = H2-1;   x = pix - H2; }
  else { int k2 = pix - 2*H2; y = 1 + (k2 >> 1); x = (k2 & 1) ? (H2-1) : 0; }
  buf[(size_t)pl*(H2*H2*32) + ((size_t)(y*H2 + x))*32 + cw] = 0;
}

__global__ void __launch_bounds__(256) zb_copy_gate(
    u16* in8, u16* t16, u16* x16, u16* t32, u16* x32,
    u16* t64, u16* x64, u16* t128, u16* x128, u16* t256,
    const float* __restrict__ downf, float4* __restrict__ dst,
    const float* __restrict__ gw, const float* __restrict__ gb,
    float* __restrict__ gateb, unsigned* __restrict__ hist)
{
  if (blockIdx.x >= 4096) {
    __shared__ unsigned lh[256];
    const int t = threadIdx.x;
    lh[t] = 0;
    __syncthreads();
    const int l = (blockIdx.x - 4096)*256 + t;
    float a0 = 0.f, a1 = 0.f, a2 = 0.f, a3 = 0.f;
    for (int c = 0; c < 256; c += 4) {
      a0 += downf[(c+0)*LL + l] * gw[c+0];
      a1 += downf[(c+1)*LL + l] * gw[c+1];
      a2 += downf[(c+2)*LL + l] * gw[c+2];
      a3 += downf[(c+3)*LL + l] * gw[c+3];
    }
    const float a = (a0+a1) + (a2+a3) + gb[0];
    const float gv = 1.f / (1.f + expf(-a));
    gateb[l] = gv;
    atomicAdd(&lh[(__float_as_uint(gv) >> 24) & 255u], 1u);
    __syncthreads();
    if (lh[t]) atomicAdd(&hist[t], lh[t]);
    return;
  }
  const int c0 = 18432,        c1 = c0 + 34816,  c2 = c1 + 34816;
  const int c3 = c2 + 67584,   c4 = c3 + 67584,  c5 = c4 + 133120;
  const int c6 = c5 + 133120,  c7 = c6 + 264192, c8 = c7 + 264192;
  const int c9 = c8 + 526336;                     // = 1544192
  const long total = (long)c9 + 4194304;          // + 64MB copy as float4
  const float4* src = (const float4*)downf;
  for (long t = (long)blockIdx.x*256 + threadIdx.x; t < total; t += (long)4096*256) {
    if (t >= c9) { dst[t - c9] = src[t - c9]; continue; }
    const int e = (int)t;
    if (e < c0)      zb_dev(in8, 10, e);
    else if (e < c1) zb_dev(t16, 18, e - c0);
    else if (e < c2) zb_dev(x16, 18, e - c1);
    else if (e < c3) zb_dev(t32, 34, e - c2);
    else if (e < c4) zb_dev(x32, 34, e - c3);
    else if (e < c5) zb_dev(t64, 66, e - c4);
    else if (e < c6) zb_dev(x64, 66, e - c5);
    else if (e < c7) zb_dev(t128, 130, e - c6);
    else if (e < c8) zb_dev(x128, 130, e - c7);
    else             zb_dev(t256, 258, e - c8);
  }
}

// ---------------------------------------------------------------------------
// Champion conv engines (16x16x32, split bf16, no LDS, barrier-free).
// This round: launch_bounds (256,2) -> (256,3). Natural VGPR use is 124
// (<170 cap), so 3 blocks/CU with no spill -> +50% wave contexts/SIMD.
// ---------------------------------------------------------------------------
template<int MI>
__global__ void __launch_bounds__(256, 3) conv3_k(
    const u16* __restrict__ in, const u16* __restrict__ W,
    const float* __restrict__ bias, u16* __restrict__ out, int H)
{
  const int H2 = H + 2;
  const int PS = H2*H2*32;
  const int tid = threadIdx.x;
  const int lane = tid & 63, wv = tid >> 6;
  const int lx = lane & 15, kg = lane >> 4;
  const int X0 = blockIdx.x*16, Y0 = blockIdx.y*(4*MI);
  const int cob = blockIdx.z;
  const int yl0 = wv*MI;

  f32x4 acc[MI][4] = {};
  const u16* Wl = W + lane*8;
  const int xoff = (X0 + lx)*32 + kg*8;

  for (int ch = 0; ch < 8; ++ch) {
    const u16* ph = in + (size_t)ch*PS;
    const u16* pl = ph + (size_t)8*PS;
    #pragma unroll
    for (int dxg = 0; dxg < 3; ++dxg) {
      s16x8 ah[MI+2], al[MI+2];
      #pragma unroll
      for (int r = 0; r < MI+2; ++r) {
        const size_t ro = (size_t)((Y0 + yl0 + r)*H2)*32 + xoff + dxg*32;
        ah[r] = *(const s16x8*)&ph[ro];
        al[r] = *(const s16x8*)&pl[ro];
      }
      #pragma unroll
      for (int dy = 0; dy < 3; ++dy) {
        const int tap = dy*3 + dxg;
        s16x8 bh[4], bl[4];
        #pragma unroll
        for (int n = 0; n < 4; ++n) {
          const int oh = (((tap*4 + cob)*4 + n)*8 + ch)*512;
          bh[n] = *(const s16x8*)&Wl[oh];
          bl[n] = *(const s16x8*)&Wl[oh + 589824];
        }
        #pragma unroll
        for (int mi = 0; mi < MI; ++mi)
          #pragma unroll
          for (int n = 0; n < 4; ++n) {
            acc[mi][n] = MFMA16(bh[n], ah[mi+dy], acc[mi][n]);
            acc[mi][n] = MFMA16(bl[n], ah[mi+dy], acc[mi][n]);
            acc[mi][n] = MFMA16(bh[n], al[mi+dy], acc[mi][n]);
          }
      }
    }
  }

  const int x = X0 + lx;
  #pragma unroll
  for (int mi = 0; mi < MI; ++mi) {
    const int y = Y0 + yl0 + mi;
    ushort4 hs[4], lo4[4];
    #pragma unroll
    for (int n = 0; n < 4; ++n) {
      const float4 bv = *(const float4*)&bias[cob*64 + n*16 + kg*4];
      const float v0 = acc[mi][n][0] + bv.x;
      const float v1 = acc[mi][n][1] + bv.y;
      const float v2 = acc[mi][n][2] + bv.z;
      const float v3 = acc[mi][n][3] + bv.w;
      const u16 h0 = f2bf(v0), h1 = f2bf(v1), h2 = f2bf(v2), h3 = f2bf(v3);
      hs[n]  = make_ushort4(h0, h1, h2, h3);
      lo4[n] = make_ushort4(f2bf(v0 - bf2f(h0)), f2bf(v1 - bf2f(h1)),
                            f2bf(v2 - bf2f(h2)), f2bf(v3 - bf2f(h3)));
    }
    const size_t ob0 = (size_t)(cob*2)*PS + ((size_t)((y+1)*H2 + x+1))*32 + kg*4;
    *(ushort4*)&out[ob0]                        = hs[0];
    *(ushort4*)&out[ob0 + 16]                   = hs[1];
    *(ushort4*)&out[ob0 + (size_t)PS]           = hs[2];
    *(ushort4*)&out[ob0 + (size_t)PS + 16]      = hs[3];
    *(ushort4*)&out[ob0 + (size_t)8*PS]         = lo4[0];
    *(ushort4*)&out[ob0 + (size_t)8*PS + 16]    = lo4[1];
    *(ushort4*)&out[ob0 + (size_t)9*PS]         = lo4[2];
    *(ushort4*)&out[ob0 + (size_t)9*PS + 16]    = lo4[3];
  }
}

template<int MI>
__global__ void __launch_bounds__(256, 3) convt_k(
    const u16* __restrict__ in, const u16* __restrict__ W,
    const float* __restrict__ bias, u16* __restrict__ out, int Hin)
{
  const int Hout = Hin*2;
  const int H2i = Hin + 2, H2o = Hout + 2;
  const int PSi = H2i*H2i*32, PSo = H2o*H2o*32;
  const int tid = threadIdx.x;
  const int lane = tid & 63, wv = tid >> 6;
  const int lx = lane & 15, kg = lane >> 4;
  const int X0 = blockIdx.x*16, Y0 = blockIdx.y*(4*MI);
  const int p = blockIdx.z >> 2, cob = blockIdx.z & 3;
  const int py = p >> 1, px = p & 1;
  const int yl0 = wv*MI;

  f32x4 acc[MI][4] = {};
  const u16* Wl = W + lane*8;
  const int xoff = (X0 + px + lx)*32 + kg*8;

  for (int ch = 0; ch < 8; ++ch) {
    const u16* ph = in + (size_t)ch*PSi;
    const u16* pl = ph + (size_t)8*PSi;
    #pragma unroll
    for (int dx = 0; dx < 2; ++dx) {
      s16x8 ah[MI+1], al[MI+1];
      #pragma unroll
      for (int r = 0; r < MI+1; ++r) {
        const size_t ro = (size_t)((Y0 + yl0 + py + r)*H2i)*32 + xoff + dx*32;
        ah[r] = *(const s16x8*)&ph[ro];
        al[r] = *(const s16x8*)&pl[ro];
      }
      #pragma unroll
      for (int dy = 0; dy < 2; ++dy) {
        const int pdt = p*4 + dy*2 + dx;
        s16x8 bh[4], bl[4];
        #pragma unroll
        for (int n = 0; n < 4; ++n) {
          const int oh = (((pdt*4 + cob)*4 + n)*8 + ch)*512;
          bh[n] = *(const s16x8*)&Wl[oh];
          bl[n] = *(const s16x8*)&Wl[oh + 1048576];
        }
        #pragma unroll
        for (int mi = 0; mi < MI; ++mi)
          #pragma unroll
          for (int n = 0; n < 4; ++n) {
            acc[mi][n] = MFMA16(bh[n], ah[mi+dy], acc[mi][n]);
            acc[mi][n] = MFMA16(bl[n], ah[mi+dy], acc[mi][n]);
            acc[mi][n] = MFMA16(bh[n], al[mi+dy], acc[mi][n]);
          }
      }
    }
  }

  const int xi = X0 + lx;
  if (xi < Hin) {
    const int X = 2*xi + px;
    #pragma unroll
    for (int mi = 0; mi < MI; ++mi) {
      const int Y = 2*(Y0 + yl0 + mi) + py;
      ushort4 hs[4], lo4[4];
      #pragma unroll
      for (int n = 0; n < 4; ++n) {
        const float4 bv = *(const float4*)&bias[cob*64 + n*16 + kg*4];
        const float v0 = fmaxf(acc[mi][n][0] + bv.x, 0.f);
        const float v1 = fmaxf(acc[mi][n][1] + bv.y, 0.f);
        const float v2 = fmaxf(acc[mi][n][2] + bv.z, 0.f);
        const float v3 = fmaxf(acc[mi][n][3] + bv.w, 0.f);
        const u16 h0 = f2bf(v0), h1 = f2bf(v1), h2 = f2bf(v2), h3 = f2bf(v3);
        hs[n]  = make_ushort4(h0, h1, h2, h3);
        lo4[n] = make_ushort4(f2bf(v0 - bf2f(h0)), f2bf(v1 - bf2f(h1)),
                              f2bf(v2 - bf2f(h2)), f2bf(v3 - bf2f(h3)));
      }
      const size_t ob0 = (size_t)(cob*2)*PSo + ((size_t)((Y+1)*H2o + X+1))*32 + kg*4;
      *(ushort4*)&out[ob0]                        = hs[0];
      *(ushort4*)&out[ob0 + 16]                   = hs[1];
      *(ushort4*)&out[ob0 + (size_t)PSo]          = hs[2];
      *(ushort4*)&out[ob0 + (size_t)PSo + 16]     = hs[3];
      *(ushort4*)&out[ob0 + (size_t)8*PSo]        = lo4[0];
      *(ushort4*)&out[ob0 + (size_t)8*PSo + 16]   = lo4[1];
      *(ushort4*)&out[ob0 + (size_t)9*PSo]        = lo4[2];
      *(ushort4*)&out[ob0 + (size_t)9*PSo + 16]   = lo4[3];
    }
  }
}

// ---------------------------------------------------------------------------
// tk_single: radix passes 1-3 + compact + tie-finalize in ONE block.
// ---------------------------------------------------------------------------
__global__ void __launch_bounds__(1024) tk_single(
    const float* __restrict__ gateb, const unsigned* __restrict__ hist,
    int* __restrict__ sel, int* __restrict__ eqbuf)
{
  __shared__ unsigned lh[256];
  __shared__ unsigned s_pref;
  __shared__ int s_kk;
  __shared__ int cgt, ceq;
  const int t = threadIdx.x;

  if (t == 0) {
    int kk = KSEL, cum = 0, b = 255;
    for (; b >= 0; --b) {
      const int c = (int)hist[b];
      if (cum + c >= kk) break;
      cum += c;
    }
    if (b < 0) b = 0;
    s_pref = (unsigned)b;
    s_kk = kk - cum;
  }
  __syncthreads();

  for (int pass = 1; pass < 4; ++pass) {
    const int shift = 24 - 8*pass;
    const unsigned pref = s_pref;
    const int kk = s_kk;
    __syncthreads();
    if (t < 256) lh[t] = 0;
    __syncthreads();
    for (int i = t; i < LL; i += 1024) {
      const unsigned u = __float_as_uint(gateb[i]);
      if ((u >> (shift + 8)) == pref) atomicAdd(&lh[(u >> shift) & 255u], 1u);
    }
    __syncthreads();
    if (t == 0) {
      int cum = 0, b = 255;
      for (; b >= 0; --b) {
        const int c = (int)lh[b];
        if (cum + c >= kk) break;
        cum += c;
      }
      if (b < 0) b = 0;
      s_pref = (pref << 8) | (unsigned)b;
      s_kk = kk - cum;
    }
    __syncthreads();
  }

  const unsigned T = s_pref;
  const int need = s_kk;
  if (t == 0) { cgt = 0; ceq = 0; }
  __syncthreads();
  for (int i = t; i < LL; i += 1024) {
    const unsigned u = __float_as_uint(gateb[i]);
    if (u > T) {
      const int p = atomicAdd(&cgt, 1);
      sel[p] = i;
    } else if (u == T) {
      const int p = atomicAdd(&ceq, 1);
      if (p < EQCAP) eqbuf[p] = i;
    }
  }
  __syncthreads();
  const int g = cgt;
  int M = ceq; if (M > EQCAP) M = EQCAP;
  for (int x = t; x < M; x += 1024) {
    const int v = eqbuf[x];
    int rank = 0;
    for (int j = 0; j < M; ++j) rank += (eqbuf[j] < v);
    if (rank < need) sel[g + rank] = v;
  }
}

// ---------------------------------------------------------------------------
// rowgemm_qkv with fused gather (kv from x256 split buffer). grid (41,3).
// ---------------------------------------------------------------------------
__global__ void __launch_bounds__(256) rowgemm_qkv(
    const float* __restrict__ WT, const float* __restrict__ down,
    const u16* __restrict__ xf, const int* __restrict__ sel,
    const float* __restrict__ bias, float* __restrict__ qkv)
{
  const int g = blockIdx.y;
  const int tid = threadIdx.x;
  const int co = g*256 + tid;
  float* outg = qkv + (size_t)g*(KSEL*256);
  __shared__ float Bl[16][256];
  __shared__ int lsh[16];
  const int n0 = blockIdx.x*16;
  if (tid < 16) lsh[tid] = (n0 + tid < KSEL) ? sel[n0 + tid] : -1;
  __syncthreads();
  const size_t PS = (size_t)258*258*32;
  #pragma unroll
  for (int j = 0; j < 16; ++j) {
    const int l = lsh[j];
    float v = 0.f;
    if (l >= 0) {
      if (g == 0) v = down[(size_t)tid*LL + l];
      else {
        const int pr = (l >> 8) + 1, pc = (l & 255) + 1;
        const size_t o = (size_t)(tid >> 5)*PS + ((size_t)(pr*258 + pc))*32 + (tid & 31);
        v = bf2f(xf[o]) + bf2f(xf[o + (size_t)8*PS]);
      }
    }
    Bl[j][tid] = v;
  }
  __syncthreads();
  float acc[16];
  const float bv = bias[co];
  #pragma unroll
  for (int j = 0; j < 16; ++j) acc[j] = bv;
  #pragma unroll 4
  for (int ci = 0; ci < 256; ++ci) {
    const float w = WT[ci*768 + co];
    #pragma unroll
    for (int j = 0; j < 16; ++j) acc[j] += Bl[j][ci]*w;
  }
  #pragma unroll
  for (int j = 0; j < 16; ++j) {
    const int n = n0 + j;
    if (n < KSEL) outg[n*256 + tid] = acc[j];
  }
}

// ---------------------------------------------------------------------------
__global__ void __launch_bounds__(256) attn_kernel(
    const float* __restrict__ qb, const float* __restrict__ kb,
    const float* __restrict__ vb, float* __restrict__ ctx)
{
  const int n = blockIdx.x, h = blockIdx.y;
  const int tid = threadIdx.x;
  __shared__ float sc[KSEL];
  __shared__ float qv[32];
  __shared__ float red[4];
  __shared__ float part[8][32];
  __shared__ float s_mx, s_sum;

  if (tid < 32) qv[tid] = qb[n*256 + h*32 + tid];
  __syncthreads();

  const float scale = 0.17677669529663687f;
  for (int m = tid; m < KSEL; m += 256) {
    const float* kr = kb + m*256 + h*32;
    float s = 0.f;
    #pragma unroll
    for (int d = 0; d < 32; ++d) s += qv[d]*kr[d];
    sc[m] = s*scale;
  }
  __syncthreads();

  float lm = -1e30f;
  for (int m = tid; m < KSEL; m += 256) lm = fmaxf(lm, sc[m]);
  #pragma unroll
  for (int off = 32; off > 0; off >>= 1) lm = fmaxf(lm, __shfl_down(lm, off));
  if ((tid & 63) == 0) red[tid >> 6] = lm;
  __syncthreads();
  if (tid == 0) s_mx = fmaxf(fmaxf(red[0], red[1]), fmaxf(red[2], red[3]));
  __syncthreads();
  const float mx = s_mx;

  float ls = 0.f;
  for (int m = tid; m < KSEL; m += 256) {
    float pv = expf(sc[m] - mx);
    sc[m] = pv;
    ls += pv;
  }
  #pragma unroll
  for (int off = 32; off > 0; off >>= 1) ls += __shfl_down(ls, off);
  if ((tid & 63) == 0) red[tid >> 6] = ls;
  __syncthreads();
  if (tid == 0) s_sum = red[0]+red[1]+red[2]+red[3];
  __syncthreads();

  const int d = tid & 31, g = tid >> 5;
  float a = 0.f;
  for (int m = g; m < KSEL; m += 8) a += sc[m]*vb[m*256 + h*32 + d];
  part[g][d] = a;
  __syncthreads();
  if (tid < 32) {
    float s = 0.f;
    #pragma unroll
    for (int gg = 0; gg < 8; ++gg) s += part[gg][tid];
    ctx[n*256 + h*32 + tid] = s / s_sum;
  }
}

// ---------------------------------------------------------------------------
// rowgemm_out with fused blend-scatter. grid (41).
// ---------------------------------------------------------------------------
__global__ void __launch_bounds__(256) rowgemm_out(
    const float* __restrict__ OWT, const float* __restrict__ ctx,
    const float* __restrict__ ob, const int* __restrict__ sel,
    const float* __restrict__ gateb, const float* __restrict__ down,
    float* __restrict__ out)
{
  const int tid = threadIdx.x;
  const int n0 = blockIdx.x*16;
  __shared__ float Bl[16][256];
  __shared__ int lsh[16];
  __shared__ float gsh[16];
  if (tid < 16) {
    const int n = n0 + tid;
    const int l = (n < KSEL) ? sel[n] : -1;
    lsh[tid] = l;
    gsh[tid] = (l >= 0) ? gateb[l] : 0.f;
  }
  __syncthreads();
  #pragma unroll
  for (int j = 0; j < 16; ++j)
    Bl[j][tid] = (lsh[j] >= 0) ? ctx[(n0 + j)*256 + tid] : 0.f;
  __syncthreads();
  float acc[16];
  const float bv = ob[tid];
  #pragma unroll
  for (int j = 0; j < 16; ++j) acc[j] = bv;
  #pragma unroll 4
  for (int ci = 0; ci < 256; ++ci) {
    const float w = OWT[ci*256 + tid];
    #pragma unroll
    for (int j = 0; j < 16; ++j) acc[j] += Bl[j][ci]*w;
  }
  #pragma unroll
  for (int j = 0; j < 16; ++j) {
    const int l = lsh[j];
    if (l >= 0) {
      const float g = gsh[j];
      const float dv = down[(size_t)tid*LL + l];
      out[(size_t)tid*LL + l] = g*acc[j] + (1.f - g)*dv;
    }
  }
}

// ---------------------------------------------------------------------------
extern "C" void kernel_launch(void* const* d_in, const int* in_sizes, int n_in,
                              void* d_out, int out_size, void* d_ws, size_t ws_size,
                              hipStream_t stream)
{
  (void)in_sizes; (void)n_in; (void)out_size; (void)ws_size;
  const float* down   = (const float*)d_in[0];
  const float* swinT  = (const float*)d_in[1];
  const float* wt_w   = (const float*)d_in[2];
  const float* wt_b   = (const float*)d_in[3];
  const float* ct_w   = (const float*)d_in[4];
  const float* ct_b   = (const float*)d_in[5];
  const float* up_w   = (const float*)d_in[6];
  const float* up_b   = (const float*)d_in[7];
  const float* gate_w = (const float*)d_in[8];
  const float* gate_b = (const float*)d_in[9];
  const float* ipw    = (const float*)d_in[10];
  const float* ipb    = (const float*)d_in[11];
  const float* ow     = (const float*)d_in[12];
  const float* ob     = (const float*)d_in[13];
  float* out = (float*)d_out;

  char* wsp = (char*)d_ws;
  size_t off = 0;
  auto take = [&](size_t bytes) -> void* {
    void* r = wsp + off;
    off += (bytes + 255) & ~(size_t)255;
    return r;
  };
  auto ubuf = [&](int H2) -> u16* {
    return (u16*)take((size_t)16*H2*H2*32*sizeof(u16));
  };
  u16* in8  = ubuf(10);
  u16* t16  = ubuf(18);  u16* x16  = ubuf(18);
  u16* t32  = ubuf(34);  u16* x32  = ubuf(34);
  u16* t64  = ubuf(66);  u16* x64  = ubuf(66);
  u16* t128 = ubuf(130); u16* x128 = ubuf(130);
  u16* t256 = ubuf(258); u16* x256 = ubuf(258);
  u16*      W3    = (u16*)     take((size_t)5898240*sizeof(u16));
  u16*      W4    = (u16*)     take((size_t)10485760*sizeof(u16));
  float*    gateb = (float*)   take((size_t)LL*sizeof(float));
  int*      sel   = (int*)     take(4096);
  unsigned* hist  = (unsigned*)take(256*sizeof(unsigned));
  int*      eqbuf = (int*)     take((size_t)EQCAP*sizeof(int));
  float*    WT    = (float*)   take((size_t)768*256*sizeof(float));
  float*    OWT   = (float*)   take((size_t)256*256*sizeof(float));
  float*    qkv   = (float*)   take((size_t)3*KSEL*256*sizeof(float));
  float*    ctx   = (float*)   take((size_t)KSEL*256*sizeof(float));

  // 1. weight prep + transposes + hist zero + conv1x1 (independent)
  prep_all<<<1281, 256, 0, stream>>>(up_w, ct_w, ipw, ow, swinT, wt_w, wt_b,
                                     W3, W4, WT, OWT, hist, in8);
  // 2. border zero + down->out copy + gate/pass-0 histogram
  zb_copy_gate<<<4352, 256, 0, stream>>>(in8, t16, x16, t32, x32, t64, x64,
                                         t128, x128, t256,
                                         down, (float4*)out,
                                         gate_w, gate_b, gateb, hist);
  // 3. top-k finish (single block)
  tk_single<<<1, 1024, 0, stream>>>(gateb, hist, sel, eqbuf);
  // 4. dense decoder (champion engines, occupancy 3 blocks/CU)
  convt_k<1><<<dim3(1, 2, 16),  256, 0, stream>>>(in8,  W4,             ct_b,        t16,  8);
  conv3_k<1><<<dim3(1, 4, 4),   256, 0, stream>>>(t16,  W3,             up_b,        x16,  16);
  convt_k<1><<<dim3(1, 4, 16),  256, 0, stream>>>(x16,  W4 + 2097152,   ct_b + 256,  t32,  16);
  conv3_k<1><<<dim3(2, 8, 4),   256, 0, stream>>>(t32,  W3 + 1179648,   up_b + 256,  x32,  32);
  convt_k<2><<<dim3(2, 4, 16),  256, 0, stream>>>(x32,  W4 + 2*2097152, ct_b + 512,  t64,  32);
  conv3_k<2><<<dim3(4, 8, 4),   256, 0, stream>>>(t64,  W3 + 2*1179648, up_b + 512,  x64,  64);
  convt_k<4><<<dim3(4, 4, 16),  256, 0, stream>>>(x64,  W4 + 3*2097152, ct_b + 768,  t128, 64);
  conv3_k<4><<<dim3(8, 8, 4),   256, 0, stream>>>(t128, W3 + 3*1179648, up_b + 768,  x128, 128);
  convt_k<4><<<dim3(8, 8, 16),  256, 0, stream>>>(x128, W4 + 4*2097152, ct_b + 1024, t256, 128);
  conv3_k<4><<<dim3(16, 16, 4), 256, 0, stream>>>(t256, W3 + 4*1179648, up_b + 1024, x256, 256);

  // 5. QKV projection with fused gather
  rowgemm_qkv<<<dim3(41, 3), 256, 0, stream>>>(WT, down, x256, sel, ipb, qkv);
  // 6. attention
  attn_kernel<<<dim3(KSEL, 8), 256, 0, stream>>>(qkv, qkv + KSEL*256,
                                                 qkv + 2*KSEL*256, ctx);
  // 7. output projection with fused blend-scatter
  rowgemm_out<<<41, 256, 0, stream>>>(OWT, ctx, ob, sel, gateb, down, out);
}

// Round 19
// 1071.893 us; speedup vs baseline: 1.3894x; 1.3894x over previous
//
#include <hip/hip_runtime.h>

#define LL 65536      // H*W
#define KSEL 655      // top-k count
#define EQCAP 8192

typedef unsigned short u16;
typedef __attribute__((ext_vector_type(8))) short s16x8;
typedef __attribute__((ext_vector_type(4))) float f32x4;

#define MFMA16(a,b,c) __builtin_amdgcn_mfma_f32_16x16x32_bf16(a,b,c,0,0,0)

__device__ __forceinline__ u16 f2bf(float v) {
  unsigned u = __float_as_uint(v);
  u += 0x7FFFu + ((u >> 16) & 1u);
  return (u16)(u >> 16);
}
__device__ __forceinline__ float bf2f(u16 h) {
  return __uint_as_float(((unsigned)h) << 16);
}

// ---------------------------------------------------------------------------
// Weight prep bodies (Round-6 verified layouts).
// ---------------------------------------------------------------------------
__device__ void prep_w3_body(int b, const float* __restrict__ up_w,
                             u16* __restrict__ W3, float* lds)
{
  const int cob = b & 3, ciq = (b >> 2) & 15, s = b >> 6;
  const int ci0 = ciq*16, ch = ciq >> 1, k0 = (ciq & 1)*2;
  const int tid = threadIdx.x;
  for (int t = tid; t < 64*144; t += 256) {
    const int co_l = t / 144, r = t - co_l*144;
    lds[co_l*145 + r] = up_w[((size_t)((s*256 + cob*64 + co_l)*256 + ci0))*9 + r];
  }
  __syncthreads();
  for (int u = tid; u < 18432; u += 256) {
    const int within = u & 255, combo = u >> 8;
    const int n = combo & 3, c2 = combo >> 2;
    const int tap = c2 % 9, hl = c2 / 9;
    const int lane_loc = within >> 3, e = within & 7;
    const int lx = lane_loc & 15, kgl = lane_loc >> 4;
    const int co_l = n*16 + lx, ci_l = kgl*8 + e;
    const float v = lds[co_l*145 + ci_l*9 + tap];
    const u16 h = f2bf(v);
    const u16 val = hl ? f2bf(v - bf2f(h)) : h;
    const size_t addr = ((size_t)(((((s*2 + hl)*9 + tap)*4 + cob)*4 + n)*8 + ch))*512
                      + k0*128 + within;
    W3[addr] = val;
  }
}

__device__ void prep_wt_body(int b, const float* __restrict__ ct_w,
                             u16* __restrict__ W4, float* lds)
{
  const int cob = b & 3, ciq = (b >> 2) & 31, s = b >> 7;
  const int ci0 = ciq*8, ch = ciq >> 2, kg = ciq & 3;
  const int tid = threadIdx.x;
  for (int t = tid; t < 8192; t += 256) {
    const int ci_l = t >> 10, r = t & 1023;
    lds[ci_l*1089 + (r >> 4)*17 + (r & 15)] =
        ct_w[((size_t)((s*256 + ci0 + ci_l)*256 + cob*64))*16 + r];
  }
  __syncthreads();
  for (int u = tid; u < 16384; u += 256) {
    const int within = u & 127, combo = u >> 7;
    const int n = combo & 3, pdt = (combo >> 2) & 15, hl = combo >> 6;
    const int lx = within >> 3, e = within & 7;
    const int p = pdt >> 2, dt = pdt & 3;
    const int py = p >> 1, px = p & 1, dy = dt >> 1, dx = dt & 1;
    const int ky = 3 - py - 2*dy, kx = 3 - px - 2*dx;
    const float v = lds[e*1089 + (n*16 + lx)*17 + ky*4 + kx];
    const u16 h = f2bf(v);
    const u16 val = hl ? f2bf(v - bf2f(h)) : h;
    const size_t addr = ((size_t)(((((s*2 + hl)*16 + pdt)*4 + cob)*4 + n)*8 + ch))*512
                      + kg*128 + within;
    W4[addr] = val;
  }
}

__device__ void transpose_body(const float* __restrict__ in, float* __restrict__ out,
                               int R, int Ck, int bx0, int by0, float* lds)
{
  float (*t)[33] = (float(*)[33])lds;
  const int bx = bx0*32, by = by0*32;
  const int x = threadIdx.x & 31, y4 = threadIdx.x >> 5;
  #pragma unroll
  for (int i = 0; i < 4; ++i) {
    int r = by + y4 + i*8, c = bx + x;
    t[y4 + i*8][x] = (r < R && c < Ck) ? in[r*Ck + c] : 0.f;
  }
  __syncthreads();
  #pragma unroll
  for (int i = 0; i < 4; ++i) {
    int c = bx + y4 + i*8, r = by + x;
    if (c < Ck && r < R) out[c*R + r] = t[x][y4 + i*8];
  }
}

// ---------------------------------------------------------------------------
// prep_all: weights + transposes + hist zero + conv1x1 (independent work).
// grid 1281.
// ---------------------------------------------------------------------------
__global__ void __launch_bounds__(256) prep_all(
    const float* __restrict__ up_w, const float* __restrict__ ct_w,
    const float* __restrict__ ipw, const float* __restrict__ ow,
    const float* __restrict__ swinT, const float* __restrict__ wt_w,
    const float* __restrict__ wt_b,
    u16* __restrict__ W3, u16* __restrict__ W4,
    float* __restrict__ WT, float* __restrict__ OWT,
    unsigned* __restrict__ hist, u16* __restrict__ in8)
{
  __shared__ float lds[9280];
  const int b = blockIdx.x;
  if (b < 320)       prep_w3_body(b, up_w, W3, lds);
  else if (b < 960)  prep_wt_body(b - 320, ct_w, W4, lds);
  else if (b < 1152) transpose_body(ipw, WT, 768, 256, (b-960) % 8, (b-960) / 8, lds);
  else if (b < 1216) transpose_body(ow, OWT, 256, 256, (b-1152) % 8, (b-1152) / 8, lds);
  else if (b == 1216) hist[threadIdx.x] = 0;
  else {
    // conv1x1: 4 co per block, 64 pixel threads per co.
    const int co = (b - 1217)*4 + (threadIdx.x >> 6);
    const int pp = threadIdx.x & 63;
    float acc = wt_b[co];
    for (int ci = 0; ci < 768; ++ci)
      acc += swinT[ci*64 + pp] * wt_w[co*768 + ci];
    const int py = pp >> 3, px = pp & 7;
    const int g = co >> 5, cw = co & 31;
    const size_t o = (size_t)g*3200 + ((size_t)((py+1)*10 + px+1))*32 + cw;
    const u16 h = f2bf(acc);
    in8[o] = h;
    in8[o + (size_t)8*3200] = f2bf(acc - bf2f(h));
  }
}

// ---------------------------------------------------------------------------
// zb_copy_gate: zero borders of all padded buffers + copy down -> out
// (blocks 0..4095) + gate+pass0 histogram (blocks 4096..4351).
// ---------------------------------------------------------------------------
__device__ __forceinline__ void zb_dev(u16* __restrict__ buf, int H2, int e)
{
  const int per = (4*H2 - 4)*32;
  const int pl = e / per, r = e - pl*per;
  const int pix = r >> 5, cw = r & 31;
  int y, x;
  if (pix < H2)        { y = 0;      x = pix; }
  else if (pix < 2*H2) { y = H2-1;   x = pix - H2; }
  else { int k2 = pix - 2*H2; y = 1 + (k2 >> 1); x = (k2 & 1) ? (H2-1) : 0; }
  buf[(size_t)pl*(H2*H2*32) + ((size_t)(y*H2 + x))*32 + cw] = 0;
}

__global__ void __launch_bounds__(256) zb_copy_gate(
    u16* in8, u16* t16, u16* x16, u16* t32, u16* x32,
    u16* t64, u16* x64, u16* t128, u16* x128, u16* t256,
    const float* __restrict__ downf, float4* __restrict__ dst,
    const float* __restrict__ gw, const float* __restrict__ gb,
    float* __restrict__ gateb, unsigned* __restrict__ hist)
{
  if (blockIdx.x >= 4096) {
    __shared__ unsigned lh[256];
    const int t = threadIdx.x;
    lh[t] = 0;
    __syncthreads();
    const int l = (blockIdx.x - 4096)*256 + t;
    float a0 = 0.f, a1 = 0.f, a2 = 0.f, a3 = 0.f;
    for (int c = 0; c < 256; c += 4) {
      a0 += downf[(c+0)*LL + l] * gw[c+0];
      a1 += downf[(c+1)*LL + l] * gw[c+1];
      a2 += downf[(c+2)*LL + l] * gw[c+2];
      a3 += downf[(c+3)*LL + l] * gw[c+3];
    }
    const float a = (a0+a1) + (a2+a3) + gb[0];
    const float gv = 1.f / (1.f + expf(-a));
    gateb[l] = gv;
    atomicAdd(&lh[(__float_as_uint(gv) >> 24) & 255u], 1u);
    __syncthreads();
    if (lh[t]) atomicAdd(&hist[t], lh[t]);
    return;
  }
  const int c0 = 18432,        c1 = c0 + 34816,  c2 = c1 + 34816;
  const int c3 = c2 + 67584,   c4 = c3 + 67584,  c5 = c4 + 133120;
  const int c6 = c5 + 133120,  c7 = c6 + 264192, c8 = c7 + 264192;
  const int c9 = c8 + 526336;                     // = 1544192
  const long total = (long)c9 + 4194304;          // + 64MB copy as float4
  const float4* src = (const float4*)downf;
  for (long t = (long)blockIdx.x*256 + threadIdx.x; t < total; t += (long)4096*256) {
    if (t >= c9) { dst[t - c9] = src[t - c9]; continue; }
    const int e = (int)t;
    if (e < c0)      zb_dev(in8, 10, e);
    else if (e < c1) zb_dev(t16, 18, e - c0);
    else if (e < c2) zb_dev(x16, 18, e - c1);
    else if (e < c3) zb_dev(t32, 34, e - c2);
    else if (e < c4) zb_dev(x32, 34, e - c3);
    else if (e < c5) zb_dev(t64, 66, e - c4);
    else if (e < c6) zb_dev(x64, 66, e - c5);
    else if (e < c7) zb_dev(t128, 130, e - c6);
    else if (e < c8) zb_dev(x128, 130, e - c7);
    else             zb_dev(t256, 258, e - c8);
  }
}

// ---------------------------------------------------------------------------
// Champion conv engines (16x16x32, split bf16, no LDS, barrier-free,
// launch_bounds (256,2): acc AGPRs + 124 VGPRs need the 2-wave budget).
// ---------------------------------------------------------------------------
template<int MI>
__global__ void __launch_bounds__(256, 2) conv3_k(
    const u16* __restrict__ in, const u16* __restrict__ W,
    const float* __restrict__ bias, u16* __restrict__ out, int H)
{
  const int H2 = H + 2;
  const int PS = H2*H2*32;
  const int tid = threadIdx.x;
  const int lane = tid & 63, wv = tid >> 6;
  const int lx = lane & 15, kg = lane >> 4;
  const int X0 = blockIdx.x*16, Y0 = blockIdx.y*(4*MI);
  const int cob = blockIdx.z;
  const int yl0 = wv*MI;

  f32x4 acc[MI][4] = {};
  const u16* Wl = W + lane*8;
  const int xoff = (X0 + lx)*32 + kg*8;

  for (int ch = 0; ch < 8; ++ch) {
    const u16* ph = in + (size_t)ch*PS;
    const u16* pl = ph + (size_t)8*PS;
    #pragma unroll
    for (int dxg = 0; dxg < 3; ++dxg) {
      s16x8 ah[MI+2], al[MI+2];
      #pragma unroll
      for (int r = 0; r < MI+2; ++r) {
        const size_t ro = (size_t)((Y0 + yl0 + r)*H2)*32 + xoff + dxg*32;
        ah[r] = *(const s16x8*)&ph[ro];
        al[r] = *(const s16x8*)&pl[ro];
      }
      #pragma unroll
      for (int dy = 0; dy < 3; ++dy) {
        const int tap = dy*3 + dxg;
        s16x8 bh[4], bl[4];
        #pragma unroll
        for (int n = 0; n < 4; ++n) {
          const int oh = (((tap*4 + cob)*4 + n)*8 + ch)*512;
          bh[n] = *(const s16x8*)&Wl[oh];
          bl[n] = *(const s16x8*)&Wl[oh + 589824];
        }
        #pragma unroll
        for (int mi = 0; mi < MI; ++mi)
          #pragma unroll
          for (int n = 0; n < 4; ++n) {
            acc[mi][n] = MFMA16(bh[n], ah[mi+dy], acc[mi][n]);
            acc[mi][n] = MFMA16(bl[n], ah[mi+dy], acc[mi][n]);
            acc[mi][n] = MFMA16(bh[n], al[mi+dy], acc[mi][n]);
          }
      }
    }
  }

  const int x = X0 + lx;
  #pragma unroll
  for (int mi = 0; mi < MI; ++mi) {
    const int y = Y0 + yl0 + mi;
    ushort4 hs[4], lo4[4];
    #pragma unroll
    for (int n = 0; n < 4; ++n) {
      const float4 bv = *(const float4*)&bias[cob*64 + n*16 + kg*4];
      const float v0 = acc[mi][n][0] + bv.x;
      const float v1 = acc[mi][n][1] + bv.y;
      const float v2 = acc[mi][n][2] + bv.z;
      const float v3 = acc[mi][n][3] + bv.w;
      const u16 h0 = f2bf(v0), h1 = f2bf(v1), h2 = f2bf(v2), h3 = f2bf(v3);
      hs[n]  = make_ushort4(h0, h1, h2, h3);
      lo4[n] = make_ushort4(f2bf(v0 - bf2f(h0)), f2bf(v1 - bf2f(h1)),
                            f2bf(v2 - bf2f(h2)), f2bf(v3 - bf2f(h3)));
    }
    const size_t ob0 = (size_t)(cob*2)*PS + ((size_t)((y+1)*H2 + x+1))*32 + kg*4;
    *(ushort4*)&out[ob0]                        = hs[0];
    *(ushort4*)&out[ob0 + 16]                   = hs[1];
    *(ushort4*)&out[ob0 + (size_t)PS]           = hs[2];
    *(ushort4*)&out[ob0 + (size_t)PS + 16]      = hs[3];
    *(ushort4*)&out[ob0 + (size_t)8*PS]         = lo4[0];
    *(ushort4*)&out[ob0 + (size_t)8*PS + 16]    = lo4[1];
    *(ushort4*)&out[ob0 + (size_t)9*PS]         = lo4[2];
    *(ushort4*)&out[ob0 + (size_t)9*PS + 16]    = lo4[3];
  }
}

template<int MI>
__global__ void __launch_bounds__(256, 2) convt_k(
    const u16* __restrict__ in, const u16* __restrict__ W,
    const float* __restrict__ bias, u16* __restrict__ out, int Hin)
{
  const int Hout = Hin*2;
  const int H2i = Hin + 2, H2o = Hout + 2;
  const int PSi = H2i*H2i*32, PSo = H2o*H2o*32;
  const int tid = threadIdx.x;
  const int lane = tid & 63, wv = tid >> 6;
  const int lx = lane & 15, kg = lane >> 4;
  const int X0 = blockIdx.x*16, Y0 = blockIdx.y*(4*MI);
  const int p = blockIdx.z >> 2, cob = blockIdx.z & 3;
  const int py = p >> 1, px = p & 1;
  const int yl0 = wv*MI;

  f32x4 acc[MI][4] = {};
  const u16* Wl = W + lane*8;
  const int xoff = (X0 + px + lx)*32 + kg*8;

  for (int ch = 0; ch < 8; ++ch) {
    const u16* ph = in + (size_t)ch*PSi;
    const u16* pl = ph + (size_t)8*PSi;
    #pragma unroll
    for (int dx = 0; dx < 2; ++dx) {
      s16x8 ah[MI+1], al[MI+1];
      #pragma unroll
      for (int r = 0; r < MI+1; ++r) {
        const size_t ro = (size_t)((Y0 + yl0 + py + r)*H2i)*32 + xoff + dx*32;
        ah[r] = *(const s16x8*)&ph[ro];
        al[r] = *(const s16x8*)&pl[ro];
      }
      #pragma unroll
      for (int dy = 0; dy < 2; ++dy) {
        const int pdt = p*4 + dy*2 + dx;
        s16x8 bh[4], bl[4];
        #pragma unroll
        for (int n = 0; n < 4; ++n) {
          const int oh = (((pdt*4 + cob)*4 + n)*8 + ch)*512;
          bh[n] = *(const s16x8*)&Wl[oh];
          bl[n] = *(const s16x8*)&Wl[oh + 1048576];
        }
        #pragma unroll
        for (int mi = 0; mi < MI; ++mi)
          #pragma unroll
          for (int n = 0; n < 4; ++n) {
            acc[mi][n] = MFMA16(bh[n], ah[mi+dy], acc[mi][n]);
            acc[mi][n] = MFMA16(bl[n], ah[mi+dy], acc[mi][n]);
            acc[mi][n] = MFMA16(bh[n], al[mi+dy], acc[mi][n]);
          }
      }
    }
  }

  const int xi = X0 + lx;
  if (xi < Hin) {
    const int X = 2*xi + px;
    #pragma unroll
    for (int mi = 0; mi < MI; ++mi) {
      const int Y = 2*(Y0 + yl0 + mi) + py;
      ushort4 hs[4], lo4[4];
      #pragma unroll
      for (int n = 0; n < 4; ++n) {
        const float4 bv = *(const float4*)&bias[cob*64 + n*16 + kg*4];
        const float v0 = fmaxf(acc[mi][n][0] + bv.x, 0.f);
        const float v1 = fmaxf(acc[mi][n][1] + bv.y, 0.f);
        const float v2 = fmaxf(acc[mi][n][2] + bv.z, 0.f);
        const float v3 = fmaxf(acc[mi][n][3] + bv.w, 0.f);
        const u16 h0 = f2bf(v0), h1 = f2bf(v1), h2 = f2bf(v2), h3 = f2bf(v3);
        hs[n]  = make_ushort4(h0, h1, h2, h3);
        lo4[n] = make_ushort4(f2bf(v0 - bf2f(h0)), f2bf(v1 - bf2f(h1)),
                              f2bf(v2 - bf2f(h2)), f2bf(v3 - bf2f(h3)));
      }
      const size_t ob0 = (size_t)(cob*2)*PSo + ((size_t)((Y+1)*H2o + X+1))*32 + kg*4;
      *(ushort4*)&out[ob0]                        = hs[0];
      *(ushort4*)&out[ob0 + 16]                   = hs[1];
      *(ushort4*)&out[ob0 + (size_t)PSo]          = hs[2];
      *(ushort4*)&out[ob0 + (size_t)PSo + 16]     = hs[3];
      *(ushort4*)&out[ob0 + (size_t)8*PSo]        = lo4[0];
      *(ushort4*)&out[ob0 + (size_t)8*PSo + 16]   = lo4[1];
      *(ushort4*)&out[ob0 + (size_t)9*PSo]        = lo4[2];
      *(ushort4*)&out[ob0 + (size_t)9*PSo + 16]   = lo4[3];
    }
  }
}

// ---------------------------------------------------------------------------
// tk_single: radix passes 1-3 + compact + tie-finalize in ONE block.
// ---------------------------------------------------------------------------
__global__ void __launch_bounds__(1024) tk_single(
    const float* __restrict__ gateb, const unsigned* __restrict__ hist,
    int* __restrict__ sel, int* __restrict__ eqbuf)
{
  __shared__ unsigned lh[256];
  __shared__ unsigned s_pref;
  __shared__ int s_kk;
  __shared__ int cgt, ceq;
  const int t = threadIdx.x;

  if (t == 0) {
    int kk = KSEL, cum = 0, b = 255;
    for (; b >= 0; --b) {
      const int c = (int)hist[b];
      if (cum + c >= kk) break;
      cum += c;
    }
    if (b < 0) b = 0;
    s_pref = (unsigned)b;
    s_kk = kk - cum;
  }
  __syncthreads();

  for (int pass = 1; pass < 4; ++pass) {
    const int shift = 24 - 8*pass;
    const unsigned pref = s_pref;
    const int kk = s_kk;
    __syncthreads();
    if (t < 256) lh[t] = 0;
    __syncthreads();
    for (int i = t; i < LL; i += 1024) {
      const unsigned u = __float_as_uint(gateb[i]);
      if ((u >> (shift + 8)) == pref) atomicAdd(&lh[(u >> shift) & 255u], 1u);
    }
    __syncthreads();
    if (t == 0) {
      int cum = 0, b = 255;
      for (; b >= 0; --b) {
        const int c = (int)lh[b];
        if (cum + c >= kk) break;
        cum += c;
      }
      if (b < 0) b = 0;
      s_pref = (pref << 8) | (unsigned)b;
      s_kk = kk - cum;
    }
    __syncthreads();
  }

  const unsigned T = s_pref;
  const int need = s_kk;
  if (t == 0) { cgt = 0; ceq = 0; }
  __syncthreads();
  for (int i = t; i < LL; i += 1024) {
    const unsigned u = __float_as_uint(gateb[i]);
    if (u > T) {
      const int p = atomicAdd(&cgt, 1);
      sel[p] = i;
    } else if (u == T) {
      const int p = atomicAdd(&ceq, 1);
      if (p < EQCAP) eqbuf[p] = i;
    }
  }
  __syncthreads();
  const int g = cgt;
  int M = ceq; if (M > EQCAP) M = EQCAP;
  for (int x = t; x < M; x += 1024) {
    const int v = eqbuf[x];
    int rank = 0;
    for (int j = 0; j < M; ++j) rank += (eqbuf[j] < v);
    if (rank < need) sel[g + rank] = v;
  }
}

// ---------------------------------------------------------------------------
// rowgemm_qkv with fused gather (kv from x256 split buffer). grid (41,3).
// ---------------------------------------------------------------------------
__global__ void __launch_bounds__(256) rowgemm_qkv(
    const float* __restrict__ WT, const float* __restrict__ down,
    const u16* __restrict__ xf, const int* __restrict__ sel,
    const float* __restrict__ bias, float* __restrict__ qkv)
{
  const int g = blockIdx.y;
  const int tid = threadIdx.x;
  const int co = g*256 + tid;
  float* outg = qkv + (size_t)g*(KSEL*256);
  __shared__ float Bl[16][256];
  __shared__ int lsh[16];
  const int n0 = blockIdx.x*16;
  if (tid < 16) lsh[tid] = (n0 + tid < KSEL) ? sel[n0 + tid] : -1;
  __syncthreads();
  const size_t PS = (size_t)258*258*32;
  #pragma unroll
  for (int j = 0; j < 16; ++j) {
    const int l = lsh[j];
    float v = 0.f;
    if (l >= 0) {
      if (g == 0) v = down[(size_t)tid*LL + l];
      else {
        const int pr = (l >> 8) + 1, pc = (l & 255) + 1;
        const size_t o = (size_t)(tid >> 5)*PS + ((size_t)(pr*258 + pc))*32 + (tid & 31);
        v = bf2f(xf[o]) + bf2f(xf[o + (size_t)8*PS]);
      }
    }
    Bl[j][tid] = v;
  }
  __syncthreads();
  float acc[16];
  const float bv = bias[co];
  #pragma unroll
  for (int j = 0; j < 16; ++j) acc[j] = bv;
  #pragma unroll 4
  for (int ci = 0; ci < 256; ++ci) {
    const float w = WT[ci*768 + co];
    #pragma unroll
    for (int j = 0; j < 16; ++j) acc[j] += Bl[j][ci]*w;
  }
  #pragma unroll
  for (int j = 0; j < 16; ++j) {
    const int n = n0 + j;
    if (n < KSEL) outg[n*256 + tid] = acc[j];
  }
}

// ---------------------------------------------------------------------------
__global__ void __launch_bounds__(256) attn_kernel(
    const float* __restrict__ qb, const float* __restrict__ kb,
    const float* __restrict__ vb, float* __restrict__ ctx)
{
  const int n = blockIdx.x, h = blockIdx.y;
  const int tid = threadIdx.x;
  __shared__ float sc[KSEL];
  __shared__ float qv[32];
  __shared__ float red[4];
  __shared__ float part[8][32];
  __shared__ float s_mx, s_sum;

  if (tid < 32) qv[tid] = qb[n*256 + h*32 + tid];
  __syncthreads();

  const float scale = 0.17677669529663687f;
  for (int m = tid; m < KSEL; m += 256) {
    const float* kr = kb + m*256 + h*32;
    float s = 0.f;
    #pragma unroll
    for (int d = 0; d < 32; ++d) s += qv[d]*kr[d];
    sc[m] = s*scale;
  }
  __syncthreads();

  float lm = -1e30f;
  for (int m = tid; m < KSEL; m += 256) lm = fmaxf(lm, sc[m]);
  #pragma unroll
  for (int off = 32; off > 0; off >>= 1) lm = fmaxf(lm, __shfl_down(lm, off));
  if ((tid & 63) == 0) red[tid >> 6] = lm;
  __syncthreads();
  if (tid == 0) s_mx = fmaxf(fmaxf(red[0], red[1]), fmaxf(red[2], red[3]));
  __syncthreads();
  const float mx = s_mx;

  float ls = 0.f;
  for (int m = tid; m < KSEL; m += 256) {
    float pv = expf(sc[m] - mx);
    sc[m] = pv;
    ls += pv;
  }
  #pragma unroll
  for (int off = 32; off > 0; off >>= 1) ls += __shfl_down(ls, off);
  if ((tid & 63) == 0) red[tid >> 6] = ls;
  __syncthreads();
  if (tid == 0) s_sum = red[0]+red[1]+red[2]+red[3];
  __syncthreads();

  const int d = tid & 31, g = tid >> 5;
  float a = 0.f;
  for (int m = g; m < KSEL; m += 8) a += sc[m]*vb[m*256 + h*32 + d];
  part[g][d] = a;
  __syncthreads();
  if (tid < 32) {
    float s = 0.f;
    #pragma unroll
    for (int gg = 0; gg < 8; ++gg) s += part[gg][tid];
    ctx[n*256 + h*32 + tid] = s / s_sum;
  }
}

// ---------------------------------------------------------------------------
// rowgemm_out with fused blend-scatter. grid (41).
// ---------------------------------------------------------------------------
__global__ void __launch_bounds__(256) rowgemm_out(
    const float* __restrict__ OWT, const float* __restrict__ ctx,
    const float* __restrict__ ob, const int* __restrict__ sel,
    const float* __restrict__ gateb, const float* __restrict__ down,
    float* __restrict__ out)
{
  const int tid = threadIdx.x;
  const int n0 = blockIdx.x*16;
  __shared__ float Bl[16][256];
  __shared__ int lsh[16];
  __shared__ float gsh[16];
  if (tid < 16) {
    const int n = n0 + tid;
    const int l = (n < KSEL) ? sel[n] : -1;
    lsh[tid] = l;
    gsh[tid] = (l >= 0) ? gateb[l] : 0.f;
  }
  __syncthreads();
  #pragma unroll
  for (int j = 0; j < 16; ++j)
    Bl[j][tid] = (lsh[j] >= 0) ? ctx[(n0 + j)*256 + tid] : 0.f;
  __syncthreads();
  float acc[16];
  const float bv = ob[tid];
  #pragma unroll
  for (int j = 0; j < 16; ++j) acc[j] = bv;
  #pragma unroll 4
  for (int ci = 0; ci < 256; ++ci) {
    const float w = OWT[ci*256 + tid];
    #pragma unroll
    for (int j = 0; j < 16; ++j) acc[j] += Bl[j][ci]*w;
  }
  #pragma unroll
  for (int j = 0; j < 16; ++j) {
    const int l = lsh[j];
    if (l >= 0) {
      const float g = gsh[j];
      const float dv = down[(size_t)tid*LL + l];
      out[(size_t)tid*LL + l] = g*acc[j] + (1.f - g)*dv;
    }
  }
}

// ---------------------------------------------------------------------------
extern "C" void kernel_launch(void* const* d_in, const int* in_sizes, int n_in,
                              void* d_out, int out_size, void* d_ws, size_t ws_size,
                              hipStream_t stream)
{
  (void)in_sizes; (void)n_in; (void)out_size; (void)ws_size;
  const float* down   = (const float*)d_in[0];
  const float* swinT  = (const float*)d_in[1];
  const float* wt_w   = (const float*)d_in[2];
  const float* wt_b   = (const float*)d_in[3];
  const float* ct_w   = (const float*)d_in[4];
  const float* ct_b   = (const float*)d_in[5];
  const float* up_w   = (const float*)d_in[6];
  const float* up_b   = (const float*)d_in[7];
  const float* gate_w = (const float*)d_in[8];
  const float* gate_b = (const float*)d_in[9];
  const float* ipw    = (const float*)d_in[10];
  const float* ipb    = (const float*)d_in[11];
  const float* ow     = (const float*)d_in[12];
  const float* ob     = (const float*)d_in[13];
  float* out = (float*)d_out;

  char* wsp = (char*)d_ws;
  size_t off = 0;
  auto take = [&](size_t bytes) -> void* {
    void* r = wsp + off;
    off += (bytes + 255) & ~(size_t)255;
    return r;
  };
  auto ubuf = [&](int H2) -> u16* {
    return (u16*)take((size_t)16*H2*H2*32*sizeof(u16));
  };
  u16* in8  = ubuf(10);
  u16* t16  = ubuf(18);  u16* x16  = ubuf(18);
  u16* t32  = ubuf(34);  u16* x32  = ubuf(34);
  u16* t64  = ubuf(66);  u16* x64  = ubuf(66);
  u16* t128 = ubuf(130); u16* x128 = ubuf(130);
  u16* t256 = ubuf(258); u16* x256 = ubuf(258);
  u16*      W3    = (u16*)     take((size_t)5898240*sizeof(u16));
  u16*      W4    = (u16*)     take((size_t)10485760*sizeof(u16));
  float*    gateb = (float*)   take((size_t)LL*sizeof(float));
  int*      sel   = (int*)     take(4096);
  unsigned* hist  = (unsigned*)take(256*sizeof(unsigned));
  int*      eqbuf = (int*)     take((size_t)EQCAP*sizeof(int));
  float*    WT    = (float*)   take((size_t)768*256*sizeof(float));
  float*    OWT   = (float*)   take((size_t)256*256*sizeof(float));
  float*    qkv   = (float*)   take((size_t)3*KSEL*256*sizeof(float));
  float*    ctx   = (float*)   take((size_t)KSEL*256*sizeof(float));

  // 1. weight prep + transposes + hist zero + conv1x1 (independent)
  prep_all<<<1281, 256, 0, stream>>>(up_w, ct_w, ipw, ow, swinT, wt_w, wt_b,
                                     W3, W4, WT, OWT, hist, in8);
  // 2. border zero + down->out copy + gate/pass-0 histogram
  zb_copy_gate<<<4352, 256, 0, stream>>>(in8, t16, x16, t32, x32, t64, x64,
                                         t128, x128, t256,
                                         down, (float4*)out,
                                         gate_w, gate_b, gateb, hist);
  // 3. top-k finish (single block)
  tk_single<<<1, 1024, 0, stream>>>(gateb, hist, sel, eqbuf);
  // 4. dense decoder (champion engines, 2 blocks/CU)
  convt_k<1><<<dim3(1, 2, 16),  256, 0, stream>>>(in8,  W4,             ct_b,        t16,  8);
  conv3_k<1><<<dim3(1, 4, 4),   256, 0, stream>>>(t16,  W3,             up_b,        x16,  16);
  convt_k<1><<<dim3(1, 4, 16),  256, 0, stream>>>(x16,  W4 + 2097152,   ct_b + 256,  t32,  16);
  conv3_k<1><<<dim3(2, 8, 4),   256, 0, stream>>>(t32,  W3 + 1179648,   up_b + 256,  x32,  32);
  convt_k<2><<<dim3(2, 4, 16),  256, 0, stream>>>(x32,  W4 + 2*2097152, ct_b + 512,  t64,  32);
  conv3_k<2><<<dim3(4, 8, 4),   256, 0, stream>>>(t64,  W3 + 2*1179648, up_b + 512,  x64,  64);
  convt_k<4><<<dim3(4, 4, 16),  256, 0, stream>>>(x64,  W4 + 3*2097152, ct_b + 768,  t128, 64);
  conv3_k<4><<<dim3(8, 8, 4),   256, 0, stream>>>(t128, W3 + 3*1179648, up_b + 768,  x128, 128);
  convt_k<4><<<dim3(8, 8, 16),  256, 0, stream>>>(x128, W4 + 4*2097152, ct_b + 1024, t256, 128);
  conv3_k<4><<<dim3(16, 16, 4), 256, 0, stream>>>(t256, W3 + 4*1179648, up_b + 1024, x256, 256);

  // 5. QKV projection with fused gather
  rowgemm_qkv<<<dim3(41, 3), 256, 0, stream>>>(WT, down, x256, sel, ipb, qkv);
  // 6. attention
  attn_kernel<<<dim3(KSEL, 8), 256, 0, stream>>>(qkv, qkv + KSEL*256,
                                                 qkv + 2*KSEL*256, ctx);
  // 7. output projection with fused blend-scatter
  rowgemm_out<<<41, 256, 0, stream>>>(OWT, ctx, ob, sel, gateb, down, out);
}